// Round 4
// baseline (173.447 us; speedup 1.0000x reference)
//
#include <hip/hip_runtime.h>
#include <hip/hip_fp16.h>
#include <math.h>

#define BB 8
#define CC 64
#define HH 128
#define WW 128
#define HO 64
#define WO 128
#define OC 64
#define HW (HH * WW)

typedef __attribute__((ext_vector_type(4))) float floatx4;
typedef __attribute__((ext_vector_type(8))) _Float16 half8;

__device__ __forceinline__ unsigned short f2h(float f) {
    __half h = __float2half(f);
    return __builtin_bit_cast(unsigned short, h);
}
__device__ __forceinline__ unsigned int packpair(float a, float b) {
    __half2 h = __floats2half2_rn(a, b);   // lo=a hi=b
    return __builtin_bit_cast(unsigned int, h);
}
// Barrier that drains ONLY LDS ops: global loads stay in flight across it.
__device__ __forceinline__ void lgkm_barrier() {
    asm volatile("s_waitcnt lgkmcnt(0)" ::: "memory");
    __builtin_amdgcn_s_barrier();
}

// ---------------------------------------------------------------------------
// Kernel A (prep) — byte-identical to rounds 2-3 (isolate the fused change).
// ---------------------------------------------------------------------------
__global__ __launch_bounds__(256) void prep(
    const float* __restrict__ x,
    const float* __restrict__ w_off, const float* __restrict__ w_msk,
    const float* __restrict__ w_conv,
    unsigned int* __restrict__ xP,
    unsigned short* __restrict__ Wom, unsigned short* __restrict__ W2)
{
    __shared__ float T[64][77];        // odd stride: col reads conflict-free
    int tid = threadIdx.x, bx = blockIdx.x;
    if (bx < 2048) {
        int wh = bx & 1, b = (bx >> 1) & 7, y = bx >> 4;
        int w0 = wh << 6;
        const float* xb = x + (((size_t)b * CC) * HH + y) * WW + w0;
#pragma unroll
        for (int i = 0; i < 4; ++i) {
            int idx = i * 256 + tid;             // 0..1023
            int cch = idx >> 4, f4 = (idx & 15) << 2;
            floatx4 v = *(const floatx4*)(xb + (size_t)cch * HW + f4);
            T[cch][f4 + 0] = v.x;
            T[cch][f4 + 1] = v.y;
            T[cch][f4 + 2] = v.z;
            T[cch][f4 + 3] = v.w;
        }
        if (tid < 64) {
            float e = 0.0f;
            if (w0 + 64 < WW) e = xb[(size_t)tid * HW + 64];
            T[tid][64] = e;
        }
        __syncthreads();
        int ch = tid & 63;
        int wb = (tid >> 6) << 4;
        size_t base = ((((size_t)b * HH + y) * WW) + w0 + wb) * 64 + ch;
#pragma unroll
        for (int j = 0; j < 4; ++j) {
            int wl = wb + 4 * j;
            float a0 = T[ch][wl + 0];
            float a1 = T[ch][wl + 1];
            float a2 = T[ch][wl + 2];
            float a3 = T[ch][wl + 3];
            float a4 = T[ch][wl + 4];
            xP[base + (size_t)(4 * j + 0) * 64] = packpair(a0, a1);
            xP[base + (size_t)(4 * j + 1) * 64] = packpair(a1, a2);
            xP[base + (size_t)(4 * j + 2) * 64] = packpair(a2, a3);
            xP[base + (size_t)(4 * j + 3) * 64] = packpair(a3, a4);
        }
    } else if (bx < 2120) {
        int i = (bx - 2048) * 256 + tid;     // < 18432 = 32*576
        int chn = i / 576, kk = i % 576;
        int xs = kk >> 6, cc = kk & 63;
        float v = 0.0f;
        if (chn < 18)      v = w_off[(chn * CC + cc) * 9 + xs];
        else if (chn < 27) v = w_msk[((chn - 18) * CC + cc) * 9 + xs];
        Wom[i] = f2h(v);
    } else {
        int i = (bx - 2120) * 256 + tid;     // < 36864
        int k = i % 9, cc = (i / 9) % CC, o = i / (CC * 9);
        W2[((size_t)k * OC + o) * CC + cc] = f2h(w_conv[i]);
    }
}

// ---------------------------------------------------------------------------
// Kernel B (fused), round-4 restructure: BARRIER-FREE main loop.
//
// Block = 64 positions (one h row-pair slab), grid 1024 = 8b*64h*2 = exactly
// 4 blocks/CU (all resident, no tail). Wave wv owns positions wv*16..+15
// (= one MFMA N-tile) and computes ALL 64 output channels for them
// (4 M-tiles, acc 16 VGPR). S tile (16pos x 64ch) is wave-PRIVATE ->
// no inter-wave sharing in the tap loop -> ZERO main-loop barriers
// (per-wave in-order DS pipe gives write->read ordering; lgkmcnt only).
// Each wave is an independent deep pipeline; per-tap FIFO order
// issueG(k+1) -> MFMA(k) -> loadA(k+1) keeps waits non-draining.
//
// Lanes in phase 4: p = lane&31 -> channel pair (2p,2p+1); ph = lane>>5 ->
// position half. Gathers are dwordx2 (both channels, both bilinear cols).
//
// LDS (35968 B, 4 blocks/CU):
//   phase 1-2: Xs[3][66][72] f16 @0 (28512) ; omr[27][68] f32 @28544 (7344)
//   phase 3-4: metaR[576] uint2 @0 ; metaC[576] uint2 @4608 ;
//              S: 2KB/wave @9216+wv*2048  (all overlay dead Xs)
// ---------------------------------------------------------------------------
__global__ __launch_bounds__(256, 4) void fused(
    const unsigned int* __restrict__ xP,
    const unsigned short* __restrict__ Wom, const unsigned short* __restrict__ W2,
    const float* __restrict__ b_off, const float* __restrict__ b_msk,
    float* __restrict__ out)
{
    __shared__ __align__(16) char lds[35968];
    _Float16* XsH = (_Float16*)lds;                 // (ky*66+col)*72 + c
    float* omr = (float*)(lds + 28544);             // [27][68]
    uint2* metaR = (uint2*)lds;                     // [9][64]
    uint2* metaC = (uint2*)(lds + 4608);            // [9][64]

    int tid = threadIdx.x;
    int lane = tid & 63;
    int wv = __builtin_amdgcn_readfirstlane(tid >> 6);
    int bx = blockIdx.x;               // 1024 = 8b * 64h * 2wt
    int b = bx & 7;
    int rest = bx >> 3;
    int h = rest >> 1;
    int w0 = (rest & 1) << 6;
    int h2 = 2 * h - 1;
    int m16 = lane & 15, q = lane >> 4;

    const unsigned int* xPb_u = xP + (size_t)b * HW * 64;

    // ---- phase 1: stage slab Xs[3][66][64ch] from xP pair-lows ----
    for (int u = tid; u < 3168; u += 256) {      // 3168 = 3*66*16
        int ky = u / 1056;
        int rem = u - ky * 1056;
        int col = rem >> 4, c4 = rem & 15;
        int hy = h2 + ky, wc = w0 - 1 + col;
        unsigned int lo0 = 0u, lo1 = 0u;
        if ((unsigned)hy < (unsigned)HH && (unsigned)wc < (unsigned)WW) {
            const uint4 g = *(const uint4*)(xPb_u + ((size_t)hy * WW + wc) * 64 + c4 * 4);
            lo0 = (g.x & 0xffffu) | (g.y << 16);
            lo1 = (g.z & 0xffffu) | (g.w << 16);
        }
        *(uint2*)(XsH + (ky * 66 + col) * 72 + c4 * 4) = make_uint2(lo0, lo1);
    }
    lgkm_barrier();

    // ---- phase 2: om GEMM  M=32(27) x N=64 x K=576; wave: Ntile=wv, Mtiles 0,1
    {
        int nt = wv;
        floatx4 a0 = (floatx4){0.f, 0.f, 0.f, 0.f};
        floatx4 a1 = (floatx4){0.f, 0.f, 0.f, 0.f};
        const _Float16* wa0 = (const _Float16*)Wom + m16 * 576 + q * 8;
        const _Float16* wa1 = wa0 + 16 * 576;
#pragma unroll
        for (int t = 0; t < 18; ++t) {
            int xs = t >> 1, ky = xs / 3, kx = xs % 3;
            half8 bf = *(const half8*)(XsH + (ky * 66 + nt * 16 + m16 + kx) * 72
                                       + (t & 1) * 32 + q * 8);
            half8 af0 = *(const half8*)(wa0 + t * 32);
            half8 af1 = *(const half8*)(wa1 + t * 32);
            a0 = __builtin_amdgcn_mfma_f32_16x16x32_f16(af0, bf, a0, 0, 0, 0);
            a1 = __builtin_amdgcn_mfma_f32_16x16x32_f16(af1, bf, a1, 0, 0, 0);
        }
#pragma unroll
        for (int r = 0; r < 4; ++r) {
            int c0 = q * 4 + r;
            omr[c0 * 68 + nt * 16 + m16] = a0[r];
            if (c0 + 16 < 27) omr[(c0 + 16) * 68 + nt * 16 + m16] = a1[r];
        }
    }
    lgkm_barrier();   // omr ready; Xs dead (meta/S overlay from here)

    // ---- phase 3: coeffs (half2) + row byte-offsets per (tap, pos 0..63) ----
    for (int u = tid; u < 576; u += 256) {
        int kk = u >> 6, pos = u & 63;
        float offy = omr[(2 * kk) * 68 + pos] + b_off[2 * kk];
        float offx = omr[(2 * kk + 1) * 68 + pos] + b_off[2 * kk + 1];
        float mk = 1.0f / (1.0f + __expf(-(omr[(18 + kk) * 68 + pos] + b_msk[kk])));
        float py = offy + (float)(kk / 3) + (float)h2;
        float px = offx + (float)(kk % 3) + (float)(w0 + pos - 1);

        float y0f = floorf(py), x0f = floorf(px);
        float dy = py - y0f, dx = px - x0f;
        int y0 = (int)y0f, x0 = (int)x0f;
        int y1 = y0 + 1, x1 = x0 + 1;
        bool vy0 = (unsigned)y0 < (unsigned)HH;
        bool vy1 = (unsigned)y1 < (unsigned)HH;
        bool vx0 = (unsigned)x0 < (unsigned)WW;
        bool vx1 = (unsigned)x1 < (unsigned)WW;
        float w00 = (1.0f - dy) * (1.0f - dx) * ((vy0 && vx0) ? mk : 0.0f);
        float w01 = (1.0f - dy) * dx          * ((vy0 && vx1) ? mk : 0.0f);
        float w10 = dy * (1.0f - dx)          * ((vy1 && vx0) ? mk : 0.0f);
        float w11 = dy * dx                   * ((vy1 && vx1) ? mk : 0.0f);
        int xbase = min(max(x0, 0), WW - 2);
        bool s0 = x0 > xbase;
        bool s1 = x1 > xbase;
        float cxA = (s0 ? 0.f : w00) + (s1 ? 0.f : w01);
        float cyA = (s0 ? w00 : 0.f) + (s1 ? w01 : 0.f);
        float cxB = (s0 ? 0.f : w10) + (s1 ? 0.f : w11);
        float cyB = (s0 ? w10 : 0.f) + (s1 ? w11 : 0.f);
        int yc0 = min(max(y0, 0), HH - 1);
        int yc1 = min(max(y1, 0), HH - 1);

        __half2 hA = __floats2half2_rn(cxA, cyA);
        __half2 hB = __floats2half2_rn(cxB, cyB);
        metaC[u] = make_uint2(__builtin_bit_cast(unsigned int, hA),
                              __builtin_bit_cast(unsigned int, hB));
        metaR[u] = make_uint2((unsigned)(yc0 * WW + xbase) * 256u,
                              (unsigned)(yc1 * WW + xbase) * 256u);
    }
    lgkm_barrier();

    // ---- phase 4: barrier-free per-wave pipeline over 9 taps ----
    int pw0 = wv * 16;                 // my 16 positions
    int p = lane & 31;                 // channel-pair (2p, 2p+1)
    int ph = lane >> 5;                // position half
    unsigned int voffC = 8u * (unsigned)p;
    const char* xPb = (const char*)xPb_u;
    char* Sw = lds + 9216 + wv * 2048; // wave-private S: [16 pos][64 ch] f16

    floatx4 acc[4];
#pragma unroll
    for (int m = 0; m < 4; ++m) acc[m] = (floatx4){0.f, 0.f, 0.f, 0.f};

    half8 A[8];                        // A frags current tap [m][ks]
    uint2 G0[8], G1[8];                // gathers current tap (8 pos x 2 rows)

    auto loadA = [&](int k) {
#pragma unroll
        for (int m = 0; m < 4; ++m)
#pragma unroll
            for (int ks = 0; ks < 2; ++ks)
                A[m * 2 + ks] = *(const half8*)((const _Float16*)W2
                    + ((size_t)(k * OC + m * 16 + m16)) * CC + ks * 32 + q * 8);
    };
    auto issueG = [&](int k) {
#pragma unroll
        for (int i = 0; i < 8; ++i) {
            uint2 zw = metaR[k * 64 + pw0 + ph * 8 + i];   // bcast per half-wave
            G0[i] = *(const uint2*)(xPb + (zw.x + voffC));
            G1[i] = *(const uint2*)(xPb + (zw.y + voffC));
        }
    };
    auto blend = [&](int k) {
#pragma unroll
        for (int i = 0; i < 8; ++i) {
            int rw = ph * 8 + i;                           // S row (0..15)
            uint2 cf = metaC[k * 64 + pw0 + rw];
            __half2 hA = __builtin_bit_cast(__half2, cf.x);
            __half2 hB = __builtin_bit_cast(__half2, cf.y);
            __half2 t0 = __hfma2(hA, __builtin_bit_cast(__half2, G0[i].x),
                                 __hmul2(hB, __builtin_bit_cast(__half2, G1[i].x)));
            __half2 t1 = __hfma2(hA, __builtin_bit_cast(__half2, G0[i].y),
                                 __hmul2(hB, __builtin_bit_cast(__half2, G1[i].y)));
            __half v0 = __hadd(__low2half(t0), __high2half(t0));
            __half v1 = __hadd(__low2half(t1), __high2half(t1));
            unsigned int d = (unsigned int)__builtin_bit_cast(unsigned short, v0)
                           | ((unsigned int)__builtin_bit_cast(unsigned short, v1) << 16);
            int cbi = p >> 2;                              // 16B ch-block (0..7)
            *(unsigned int*)(Sw + rw * 128 + ((cbi ^ (rw & 7)) * 16 + (p & 3) * 4)) = d;
        }
    };
    auto mfma_tap = [&]() {
        half8 Bf[2];
#pragma unroll
        for (int ks = 0; ks < 2; ++ks) {
            int cbi = ks * 4 + q;
            Bf[ks] = *(const half8*)(Sw + m16 * 128 + ((cbi ^ (m16 & 7)) * 16));
        }
#pragma unroll
        for (int m = 0; m < 4; ++m)
#pragma unroll
            for (int ks = 0; ks < 2; ++ks)
                acc[m] = __builtin_amdgcn_mfma_f32_16x16x32_f16(A[m * 2 + ks], Bf[ks],
                                                                acc[m], 0, 0, 0);
    };

    // prologue: FIFO [A(0), G(0)] — blend(0)'s wait on G(0) retires A(0) too
    loadA(0);
    issueG(0);
#pragma unroll
    for (int k = 0; k < 9; ++k) {
        blend(k);                      // vmcnt wait on G(k); S writes
        if (k < 8) issueG(k + 1);      // G in flight across MFMA + next blend
        mfma_tap();                    // lgkm wait (S+meta), A(k) already home
        if (k < 8) loadA(k + 1);       // younger than G(k+1): waits don't drain
    }

    // epilogue: C/D col=lane&15 (pos), row=(lane>>4)*4+reg (o within tile)
#pragma unroll
    for (int m = 0; m < 4; ++m)
#pragma unroll
        for (int r = 0; r < 4; ++r) {
            int o = m * 16 + q * 4 + r;
            out[(((size_t)b * OC + o) * HO + h) * WO + w0 + pw0 + m16] = acc[m][r];
        }
}

// ---------------------------------------------------------------------------
extern "C" void kernel_launch(void* const* d_in, const int* in_sizes, int n_in,
                              void* d_out, int out_size, void* d_ws, size_t ws_size,
                              hipStream_t stream)
{
    const float* x      = (const float*)d_in[0];
    const float* w_off  = (const float*)d_in[1];
    const float* b_off  = (const float*)d_in[2];
    const float* w_msk  = (const float*)d_in[3];
    const float* b_msk  = (const float*)d_in[4];
    const float* w_conv = (const float*)d_in[5];
    float* out = (float*)d_out;

    // workspace (~33.7 MB): xP f16-pair uints, Wom, W2
    unsigned int* xP = (unsigned int*)d_ws;                       // 8*HW*64 * 4B
    unsigned short* Wom = (unsigned short*)(xP + (size_t)BB * HW * 64); // 32*576
    unsigned short* W2 = Wom + 32 * 576;                          // 36864

    prep<<<dim3(2264), dim3(256), 0, stream>>>(x, w_off, w_msk, w_conv,
                                               xP, Wom, W2);
    fused<<<dim3(1024), dim3(256), 0, stream>>>(xP, Wom, W2,
                                                b_off, b_msk, out);
}

// Round 5
// 166.158 us; speedup vs baseline: 1.0439x; 1.0439x over previous
//
#include <hip/hip_runtime.h>
#include <hip/hip_fp16.h>
#include <math.h>

#define BB 8
#define CC 64
#define HH 128
#define WW 128
#define HO 64
#define WO 128
#define OC 64
#define HW (HH * WW)

typedef __attribute__((ext_vector_type(4))) float floatx4;
typedef __attribute__((ext_vector_type(8))) _Float16 half8;

__device__ __forceinline__ unsigned short f2h(float f) {
    __half h = __float2half(f);
    return __builtin_bit_cast(unsigned short, h);
}
__device__ __forceinline__ unsigned int packpair(float a, float b) {
    __half2 h = __floats2half2_rn(a, b);   // lo=a hi=b
    return __builtin_bit_cast(unsigned int, h);
}
// Barrier that drains ONLY LDS ops: global loads stay in flight across it.
__device__ __forceinline__ void lgkm_barrier() {
    asm volatile("s_waitcnt lgkmcnt(0)" ::: "memory");
    __builtin_amdgcn_s_barrier();
}

// ---------------------------------------------------------------------------
// Kernel A (prep), round-5 rework of the transpose slabs:
// LDS layout is now T[w][c] (stride 65 dwords: conflict-free writes AND
// b128 reads) so phase B produces one uint4 (4 consecutive channels) per
// read-pair -> global_store_dwordx4 (4 stores/thread instead of 16 scalar).
//  blocks 0..2047   : transpose x -> xP[b][y][w][c] = (f16 col w, f16 col w+1)
//  blocks 2048..2119: Wom[32][576] f16
//  blocks 2120..2263: W2[k][o][c] f16
// ---------------------------------------------------------------------------
__global__ __launch_bounds__(256) void prep(
    const float* __restrict__ x,
    const float* __restrict__ w_off, const float* __restrict__ w_msk,
    const float* __restrict__ w_conv,
    unsigned int* __restrict__ xP,
    unsigned short* __restrict__ Wom, unsigned short* __restrict__ W2)
{
    __shared__ float T[66][65];        // [w 0..64][c 0..63], stride 65
    int tid = threadIdx.x, bx = blockIdx.x;
    if (bx < 2048) {
        int wh = bx & 1, b = (bx >> 1) & 7, y = bx >> 4;
        int w0 = wh << 6;
        const float* xb = x + (((size_t)b * CC) * HH + y) * WW + w0;
        // phase A: 64 ch x 64 w as float4 loads; transposed scalar LDS writes
        // write bank = ((f4+r)*65 + c) % 32 -> stride-65 keeps 16-lane groups
        // spread (8 banks x 2-way = free)
#pragma unroll
        for (int i = 0; i < 4; ++i) {
            int idx = i * 256 + tid;             // 0..1023
            int cch = idx >> 4, f4 = (idx & 15) << 2;
            floatx4 v = *(const floatx4*)(xb + (size_t)cch * HW + f4);
            T[f4 + 0][cch] = v.x;
            T[f4 + 1][cch] = v.y;
            T[f4 + 2][cch] = v.z;
            T[f4 + 3][cch] = v.w;
        }
        // extra column w0+64 (pair partner of w0+63); 0 past right edge
        if (tid < 64) {
            float e = 0.0f;
            if (w0 + 64 < WW) e = xb[(size_t)tid * HW + 64];
            T[64][tid] = e;
        }
        __syncthreads();
        // phase B: thread = (w, 4-channel block). 2x ds_read_b128 ->
        // 4x v_cvt_pkrtz -> 1x global_store_dwordx4 (1KB/wave-instr).
        int c4 = tid & 15;             // channel block (4c4..4c4+3)
        int wr = tid >> 4;             // 0..15
        size_t rowbase = (((size_t)b * HH + y) * WW) + w0;
#pragma unroll
        for (int j = 0; j < 4; ++j) {
            int w = 16 * j + wr;
            floatx4 a  = *(const floatx4*)&T[w][4 * c4];
            floatx4 bb = *(const floatx4*)&T[w + 1][4 * c4];
            uint4 d;
            d.x = packpair(a.x, bb.x);
            d.y = packpair(a.y, bb.y);
            d.z = packpair(a.z, bb.z);
            d.w = packpair(a.w, bb.w);
            *(uint4*)(xP + (rowbase + w) * 64 + 4 * c4) = d;
        }
    } else if (bx < 2120) {
        int i = (bx - 2048) * 256 + tid;     // < 18432 = 32*576
        int chn = i / 576, kk = i % 576;
        int xs = kk >> 6, cc = kk & 63;
        float v = 0.0f;
        if (chn < 18)      v = w_off[(chn * CC + cc) * 9 + xs];
        else if (chn < 27) v = w_msk[((chn - 18) * CC + cc) * 9 + xs];
        Wom[i] = f2h(v);
    } else {
        int i = (bx - 2120) * 256 + tid;     // < 36864
        int k = i % 9, cc = (i / 9) % CC, o = i / (CC * 9);
        W2[((size_t)k * OC + o) * CC + cc] = f2h(w_conv[i]);
    }
}

// ---------------------------------------------------------------------------
// Kernel B (fused): barrier-free main loop (round-4 structure), round-5
// register fixes:
//  * __launch_bounds__(256, 2): round-4's (256,4) split the unified 128-reg
//    budget 64 arch + 64 acc -> ~100-reg live set spilled 27 MB/iter.
//    Occupancy stays LDS-capped at 4 blocks/CU while regs <= 128.
//  * #pragma unroll 1 on the 9-tap loop: live set = ONE tap's pipeline;
//    stops cross-tap load hoisting that inflated pressure.
// ---------------------------------------------------------------------------
__global__ __launch_bounds__(256, 2) void fused(
    const unsigned int* __restrict__ xP,
    const unsigned short* __restrict__ Wom, const unsigned short* __restrict__ W2,
    const float* __restrict__ b_off, const float* __restrict__ b_msk,
    float* __restrict__ out)
{
    __shared__ __align__(16) char lds[35968];
    _Float16* XsH = (_Float16*)lds;                 // (ky*66+col)*72 + c
    float* omr = (float*)(lds + 28544);             // [27][68]
    uint2* metaR = (uint2*)lds;                     // [9][64]
    uint2* metaC = (uint2*)(lds + 4608);            // [9][64]

    int tid = threadIdx.x;
    int lane = tid & 63;
    int wv = __builtin_amdgcn_readfirstlane(tid >> 6);
    int bx = blockIdx.x;               // 1024 = 8b * 64h * 2wt
    int b = bx & 7;
    int rest = bx >> 3;
    int h = rest >> 1;
    int w0 = (rest & 1) << 6;
    int h2 = 2 * h - 1;
    int m16 = lane & 15, q = lane >> 4;

    const unsigned int* xPb_u = xP + (size_t)b * HW * 64;

    // ---- phase 1: stage slab Xs[3][66][64ch] from xP pair-lows ----
    for (int u = tid; u < 3168; u += 256) {      // 3168 = 3*66*16
        int ky = u / 1056;
        int rem = u - ky * 1056;
        int col = rem >> 4, c4 = rem & 15;
        int hy = h2 + ky, wc = w0 - 1 + col;
        unsigned int lo0 = 0u, lo1 = 0u;
        if ((unsigned)hy < (unsigned)HH && (unsigned)wc < (unsigned)WW) {
            const uint4 g = *(const uint4*)(xPb_u + ((size_t)hy * WW + wc) * 64 + c4 * 4);
            lo0 = (g.x & 0xffffu) | (g.y << 16);
            lo1 = (g.z & 0xffffu) | (g.w << 16);
        }
        *(uint2*)(XsH + (ky * 66 + col) * 72 + c4 * 4) = make_uint2(lo0, lo1);
    }
    lgkm_barrier();

    // ---- phase 2: om GEMM  M=32(27) x N=64 x K=576; wave: Ntile=wv, Mtiles 0,1
    {
        int nt = wv;
        floatx4 a0 = (floatx4){0.f, 0.f, 0.f, 0.f};
        floatx4 a1 = (floatx4){0.f, 0.f, 0.f, 0.f};
        const _Float16* wa0 = (const _Float16*)Wom + m16 * 576 + q * 8;
        const _Float16* wa1 = wa0 + 16 * 576;
#pragma unroll
        for (int t = 0; t < 18; ++t) {
            int xs = t >> 1, ky = xs / 3, kx = xs % 3;
            half8 bf = *(const half8*)(XsH + (ky * 66 + nt * 16 + m16 + kx) * 72
                                       + (t & 1) * 32 + q * 8);
            half8 af0 = *(const half8*)(wa0 + t * 32);
            half8 af1 = *(const half8*)(wa1 + t * 32);
            a0 = __builtin_amdgcn_mfma_f32_16x16x32_f16(af0, bf, a0, 0, 0, 0);
            a1 = __builtin_amdgcn_mfma_f32_16x16x32_f16(af1, bf, a1, 0, 0, 0);
        }
#pragma unroll
        for (int r = 0; r < 4; ++r) {
            int c0 = q * 4 + r;
            omr[c0 * 68 + nt * 16 + m16] = a0[r];
            if (c0 + 16 < 27) omr[(c0 + 16) * 68 + nt * 16 + m16] = a1[r];
        }
    }
    lgkm_barrier();   // omr ready; Xs dead (meta/S overlay from here)

    // ---- phase 3: coeffs (half2) + row byte-offsets per (tap, pos 0..63) ----
    for (int u = tid; u < 576; u += 256) {
        int kk = u >> 6, pos = u & 63;
        float offy = omr[(2 * kk) * 68 + pos] + b_off[2 * kk];
        float offx = omr[(2 * kk + 1) * 68 + pos] + b_off[2 * kk + 1];
        float mk = 1.0f / (1.0f + __expf(-(omr[(18 + kk) * 68 + pos] + b_msk[kk])));
        float py = offy + (float)(kk / 3) + (float)h2;
        float px = offx + (float)(kk % 3) + (float)(w0 + pos - 1);

        float y0f = floorf(py), x0f = floorf(px);
        float dy = py - y0f, dx = px - x0f;
        int y0 = (int)y0f, x0 = (int)x0f;
        int y1 = y0 + 1, x1 = x0 + 1;
        bool vy0 = (unsigned)y0 < (unsigned)HH;
        bool vy1 = (unsigned)y1 < (unsigned)HH;
        bool vx0 = (unsigned)x0 < (unsigned)WW;
        bool vx1 = (unsigned)x1 < (unsigned)WW;
        float w00 = (1.0f - dy) * (1.0f - dx) * ((vy0 && vx0) ? mk : 0.0f);
        float w01 = (1.0f - dy) * dx          * ((vy0 && vx1) ? mk : 0.0f);
        float w10 = dy * (1.0f - dx)          * ((vy1 && vx0) ? mk : 0.0f);
        float w11 = dy * dx                   * ((vy1 && vx1) ? mk : 0.0f);
        int xbase = min(max(x0, 0), WW - 2);
        bool s0 = x0 > xbase;
        bool s1 = x1 > xbase;
        float cxA = (s0 ? 0.f : w00) + (s1 ? 0.f : w01);
        float cyA = (s0 ? w00 : 0.f) + (s1 ? w01 : 0.f);
        float cxB = (s0 ? 0.f : w10) + (s1 ? 0.f : w11);
        float cyB = (s0 ? w10 : 0.f) + (s1 ? w11 : 0.f);
        int yc0 = min(max(y0, 0), HH - 1);
        int yc1 = min(max(y1, 0), HH - 1);

        __half2 hA = __floats2half2_rn(cxA, cyA);
        __half2 hB = __floats2half2_rn(cxB, cyB);
        metaC[u] = make_uint2(__builtin_bit_cast(unsigned int, hA),
                              __builtin_bit_cast(unsigned int, hB));
        metaR[u] = make_uint2((unsigned)(yc0 * WW + xbase) * 256u,
                              (unsigned)(yc1 * WW + xbase) * 256u);
    }
    lgkm_barrier();

    // ---- phase 4: barrier-free per-wave pipeline over 9 taps ----
    int pw0 = wv * 16;                 // my 16 positions
    int p = lane & 31;                 // channel-pair (2p, 2p+1)
    int ph = lane >> 5;                // position half
    unsigned int voffC = 8u * (unsigned)p;
    const char* xPb = (const char*)xPb_u;
    char* Sw = lds + 9216 + wv * 2048; // wave-private S: [16 pos][64 ch] f16

    floatx4 acc[4];
#pragma unroll
    for (int m = 0; m < 4; ++m) acc[m] = (floatx4){0.f, 0.f, 0.f, 0.f};

    half8 A[8];                        // A frags current tap [m][ks]
    uint2 G0[8], G1[8];                // gathers current tap (8 pos x 2 rows)

    auto loadA = [&](int k) {
#pragma unroll
        for (int m = 0; m < 4; ++m)
#pragma unroll
            for (int ks = 0; ks < 2; ++ks)
                A[m * 2 + ks] = *(const half8*)((const _Float16*)W2
                    + ((size_t)(k * OC + m * 16 + m16)) * CC + ks * 32 + q * 8);
    };
    auto issueG = [&](int k) {
#pragma unroll
        for (int i = 0; i < 8; ++i) {
            uint2 zw = metaR[k * 64 + pw0 + ph * 8 + i];   // bcast per half-wave
            G0[i] = *(const uint2*)(xPb + (zw.x + voffC));
            G1[i] = *(const uint2*)(xPb + (zw.y + voffC));
        }
    };
    auto blend = [&](int k) {
#pragma unroll
        for (int i = 0; i < 8; ++i) {
            int rw = ph * 8 + i;                           // S row (0..15)
            uint2 cf = metaC[k * 64 + pw0 + rw];
            __half2 hA = __builtin_bit_cast(__half2, cf.x);
            __half2 hB = __builtin_bit_cast(__half2, cf.y);
            __half2 t0 = __hfma2(hA, __builtin_bit_cast(__half2, G0[i].x),
                                 __hmul2(hB, __builtin_bit_cast(__half2, G1[i].x)));
            __half2 t1 = __hfma2(hA, __builtin_bit_cast(__half2, G0[i].y),
                                 __hmul2(hB, __builtin_bit_cast(__half2, G1[i].y)));
            __half v0 = __hadd(__low2half(t0), __high2half(t0));
            __half v1 = __hadd(__low2half(t1), __high2half(t1));
            unsigned int d = (unsigned int)__builtin_bit_cast(unsigned short, v0)
                           | ((unsigned int)__builtin_bit_cast(unsigned short, v1) << 16);
            int cbi = p >> 2;                              // 16B ch-block (0..7)
            *(unsigned int*)(Sw + rw * 128 + ((cbi ^ (rw & 7)) * 16 + (p & 3) * 4)) = d;
        }
    };
    auto mfma_tap = [&]() {
        half8 Bf[2];
#pragma unroll
        for (int ks = 0; ks < 2; ++ks) {
            int cbi = ks * 4 + q;
            Bf[ks] = *(const half8*)(Sw + m16 * 128 + ((cbi ^ (m16 & 7)) * 16));
        }
#pragma unroll
        for (int m = 0; m < 4; ++m)
#pragma unroll
            for (int ks = 0; ks < 2; ++ks)
                acc[m] = __builtin_amdgcn_mfma_f32_16x16x32_f16(A[m * 2 + ks], Bf[ks],
                                                                acc[m], 0, 0, 0);
    };

    // prologue: FIFO [A(0), G(0)] — blend(0)'s wait on G(0) retires A(0) too
    loadA(0);
    issueG(0);
#pragma unroll 1
    for (int k = 0; k < 9; ++k) {
        blend(k);                      // vmcnt wait on G(k); S writes
        if (k < 8) issueG(k + 1);      // G in flight across MFMA + next blend
        mfma_tap();                    // lgkm wait (S+meta), A(k) already home
        if (k < 8) loadA(k + 1);       // younger than G(k+1): waits don't drain
    }

    // epilogue: C/D col=lane&15 (pos), row=(lane>>4)*4+reg (o within tile)
#pragma unroll
    for (int m = 0; m < 4; ++m)
#pragma unroll
        for (int r = 0; r < 4; ++r) {
            int o = m * 16 + q * 4 + r;
            out[(((size_t)b * OC + o) * HO + h) * WO + w0 + pw0 + m16] = acc[m][r];
        }
}

// ---------------------------------------------------------------------------
extern "C" void kernel_launch(void* const* d_in, const int* in_sizes, int n_in,
                              void* d_out, int out_size, void* d_ws, size_t ws_size,
                              hipStream_t stream)
{
    const float* x      = (const float*)d_in[0];
    const float* w_off  = (const float*)d_in[1];
    const float* b_off  = (const float*)d_in[2];
    const float* w_msk  = (const float*)d_in[3];
    const float* b_msk  = (const float*)d_in[4];
    const float* w_conv = (const float*)d_in[5];
    float* out = (float*)d_out;

    // workspace (~33.7 MB): xP f16-pair uints, Wom, W2
    unsigned int* xP = (unsigned int*)d_ws;                       // 8*HW*64 * 4B
    unsigned short* Wom = (unsigned short*)(xP + (size_t)BB * HW * 64); // 32*576
    unsigned short* W2 = Wom + 32 * 576;                          // 36864

    prep<<<dim3(2264), dim3(256), 0, stream>>>(x, w_off, w_msk, w_conv,
                                               xP, Wom, W2);
    fused<<<dim3(1024), dim3(256), 0, stream>>>(xP, Wom, W2,
                                                b_off, b_msk, out);
}